// Round 3
// baseline (1073.998 us; speedup 1.0000x reference)
//
#include <hip/hip_runtime.h>

// ConvQuad2D as ONE pure GEMM over symmetrized pair-features (no stage-2):
//   quad[pix,o] = sum_{d, i<=j} (p_i p_j) * Wsym[d,i,j,o],  Wsym = W + W^T (off-diag)
//   lin[pix,o]  = sum_{d, i}    p_i       * Klin[i,d,o]
// K-slot mapping (our choice, prep kernel matches): k = (c,q,e) -> channel d=q,
// feature f=c*8+e in [0,352): f<325 pair (i<=j), f<350 linear p_{f-325}, else pad 0.
// => each lane (m=lane&15 pixel, q=lane>>4 channel) computes its 8 A-frag halfs
//    per chunk from a STATICALLY-indexed pd[25] register patch. No LDS for A,
//    no cross-lane traffic, no mfma->VALU dependency (r2 was latency-bound on it).
// B-fragments (44 KB) staged to LDS once per block; 44 conflict-free ds_read_b128
// per wave. Two 16-pix tiles per wave (32 pix) halve B traffic.

typedef _Float16 half8 __attribute__((ext_vector_type(8)));
typedef float floatx4 __attribute__((ext_vector_type(4)));

#define BB 8
#define HH 250
#define WW 250
#define NPIX (BB * HH * WW)   // 500,000
#define NF 16
#define NPAIR 325             // i<=j pairs of 25
#define NCHUNK 44             // 44*8 = 352 features/channel; K = 4*352 = 1408

__host__ __device__ constexpr int pair_i(int f) {
    int i = 0, r = f;
    while (r >= 25 - i) { r -= 25 - i; ++i; }
    return i;
}
__host__ __device__ constexpr int pair_j(int f) {
    int i = 0, r = f;
    while (r >= 25 - i) { r -= 25 - i; ++i; }
    return i + r;
}

// ---------- pre-pass: B fragments in MFMA lane order ----------
// fragB[(c*64+lane)*8 + e] : B[k=(c,q,e)][n], lane=(q<<4)|n
__global__ void prep_frags(const float* __restrict__ lin_w,   // (5,5,4,16)
                           const float* __restrict__ quad_w,  // (4,25,25,16)
                           _Float16* __restrict__ fragB) {
    const int c = blockIdx.x;       // 0..43
    const int lane = threadIdx.x;   // 0..63
    const int n = lane & 15;
    const int d = lane >> 4;
    half8 frag;
    #pragma unroll
    for (int e = 0; e < 8; ++e) {
        const int f = c * 8 + e;
        float v = 0.f;
        if (f < NPAIR) {
            int i = 0, r = f;
            while (r >= 25 - i) { r -= 25 - i; ++i; }
            const int j = i + r;
            v = quad_w[((d * 25 + i) * 25 + j) * 16 + n];
            if (i != j) v += quad_w[((d * 25 + j) * 25 + i) * 16 + n];
        } else if (f < NPAIR + 25) {
            const int i = f - NPAIR;
            v = lin_w[i * 64 + d * 16 + n];
        }
        frag[e] = (_Float16)v;
    }
    *(half8*)(fragB + (c * 64 + lane) * 8) = frag;
}

// ---------- main kernel: 32 pixels per wave, 4 waves per block ----------
__global__ __launch_bounds__(256) void convquad_gemm(
    const float* __restrict__ x,       // (8,250,250,4)
    const float* __restrict__ bias,    // (16,)
    const _Float16* __restrict__ fragB,
    float* __restrict__ out)           // (8,250,250,16)
{
    __shared__ _Float16 sB[NCHUNK * 64 * 8];   // 45,056 B

    {   // stage B fragments (block-wide, once)
        const float4* src = (const float4*)fragB;
        float4* dst = (float4*)sB;
        #pragma unroll
        for (int t = threadIdx.x; t < NCHUNK * 64 * 8 / 8; t += 256) dst[t] = src[t];
    }
    __syncthreads();

    const int lane = threadIdx.x & 63;
    const int wave = threadIdx.x >> 6;
    const int m = lane & 15;     // pixel-in-tile (A rows), also o for the store
    const int q = lane >> 4;     // channel d for A; row-quad for D
    const int pixbase = blockIdx.x * 128 + wave * 32;

    // ---- per-lane patch of 2 pixels, channel q, statically indexed ----
    float pd[2][25];
    #pragma unroll
    for (int t = 0; t < 2; ++t) {
        const int pix = pixbase + t * 16 + m;
        const int pixc = min(pix, NPIX - 1);
        const int w  = pixc % WW;
        const int t1 = pixc / WW;
        const int h  = t1 % HH;
        const int b  = t1 / HH;
        #pragma unroll
        for (int kh = 0; kh < 5; ++kh) {
            const int r = h + kh - 2;
            const float rm = (r >= 0 && r < HH) ? 1.f : 0.f;
            const int rc = min(max(r, 0), HH - 1);
            const int rowb = ((b * HH + rc) * WW) * 4;
            #pragma unroll
            for (int kw = 0; kw < 5; ++kw) {
                const int c = w + kw - 2;
                const float cm = (c >= 0 && c < WW) ? 1.f : 0.f;
                const int cc = min(max(c, 0), WW - 1);
                pd[t][kh * 5 + kw] = x[rowb + cc * 4 + q] * (rm * cm);
            }
        }
    }

    // ---- GEMM: 44 chunks, features generated in-register ----
    floatx4 acc0 = {0.f, 0.f, 0.f, 0.f};
    floatx4 acc1 = {0.f, 0.f, 0.f, 0.f};
    const half8* sBv = (const half8*)sB;
    #pragma unroll
    for (int c = 0; c < NCHUNK; ++c) {
        half8 af0, af1;
        #pragma unroll
        for (int e = 0; e < 8; ++e) {
            const int f = c * 8 + e;
            float v0, v1;
            if (f < NPAIR) {
                const int i = pair_i(f), j = pair_j(f);
                v0 = pd[0][i] * pd[0][j];
                v1 = pd[1][i] * pd[1][j];
            } else if (f < NPAIR + 25) {
                v0 = pd[0][f - NPAIR];
                v1 = pd[1][f - NPAIR];
            } else {
                v0 = 0.f; v1 = 0.f;
            }
            af0[e] = (_Float16)v0;
            af1[e] = (_Float16)v1;
        }
        const half8 bf = sBv[c * 64 + lane];
        acc0 = __builtin_amdgcn_mfma_f32_16x16x32_f16(af0, bf, acc0, 0, 0, 0);
        acc1 = __builtin_amdgcn_mfma_f32_16x16x32_f16(af1, bf, acc1, 0, 0, 0);
    }

    // ---- epilogue: D[row=q*4+r][o=m] + bias ----
    const float bo = bias[m];
    #pragma unroll
    for (int r = 0; r < 4; ++r) {
        const int p0 = pixbase + q * 4 + r;
        if (p0 < NPIX) out[p0 * NF + m] = acc0[r] + bo;
        const int p1 = pixbase + 16 + q * 4 + r;
        if (p1 < NPIX) out[p1 * NF + m] = acc1[r] + bo;
    }
}

extern "C" void kernel_launch(void* const* d_in, const int* in_sizes, int n_in,
                              void* d_out, int out_size, void* d_ws, size_t ws_size,
                              hipStream_t stream) {
    const float* x      = (const float*)d_in[0];
    const float* lin_w  = (const float*)d_in[1];
    const float* quad_w = (const float*)d_in[2];
    const float* bias   = (const float*)d_in[3];
    float* out = (float*)d_out;
    _Float16* fragB = (_Float16*)d_ws;   // 45,056 B

    prep_frags<<<dim3(NCHUNK), dim3(64), 0, stream>>>(lin_w, quad_w, fragB);

    const int nblocks = (NPIX + 127) / 128;   // 3907 blocks, 32 pix/wave
    convquad_gemm<<<dim3(nblocks), dim3(256), 0, stream>>>(x, bias, fragB, out);
}

// Round 4
// 168.151 us; speedup vs baseline: 6.3871x; 6.3871x over previous
//
#include <hip/hip_runtime.h>
#include <utility>

// ConvQuad2D as ONE pure GEMM over symmetrized pair-features (no stage-2):
//   quad[pix,o] = sum_{d, i<=j} (p_i p_j) * Wsym[d,i,j,o],  Wsym = W + W^T (off-diag)
//   lin[pix,o]  = sum_{d, i}    p_i       * Klin[i,d,o]     (constant-weight column)
// K-slot mapping: k=(q,e) in chunk c -> channel d=q, feature f=c*8+e in [0,352):
//   f<325 pair (i<=j), f<350 linear p_{f-325}, else pad 0.
//
// Round-3 post-mortem: #pragma unroll failed to constant-fold f through
// pair_i/pair_j -> pd[] dynamically indexed -> spilled to scratch (VGPR=68,
// +400 MB HBM scratch traffic, 1074 us). Fix: template-parameter unrolling —
// every (C,E) is a compile-time constant, pd[] indices are literals, arrays
// stay in VGPRs by construction.

typedef _Float16 half8 __attribute__((ext_vector_type(8)));
typedef float floatx4 __attribute__((ext_vector_type(4)));

#define BB 8
#define HH 250
#define WW 250
#define NPIX (BB * HH * WW)   // 500,000
#define NF 16
#define NPAIR 325             // i<=j pairs of 25
#define NCHUNK 44             // 44*8 = 352 features/channel

__host__ __device__ constexpr int pair_i(int f) {
    int i = 0, r = f;
    while (r >= 25 - i) { r -= 25 - i; ++i; }
    return i;
}
__host__ __device__ constexpr int pair_j(int f) {
    int i = 0, r = f;
    while (r >= 25 - i) { r -= 25 - i; ++i; }
    return i + r;
}

// ---------- pre-pass: B fragments in MFMA lane order ----------
__global__ void prep_frags(const float* __restrict__ lin_w,   // (5,5,4,16)
                           const float* __restrict__ quad_w,  // (4,25,25,16)
                           _Float16* __restrict__ fragB) {
    const int c = blockIdx.x;       // 0..43
    const int lane = threadIdx.x;   // 0..63
    const int n = lane & 15;
    const int d = lane >> 4;
    half8 frag;
    #pragma unroll
    for (int e = 0; e < 8; ++e) {
        const int f = c * 8 + e;
        float v = 0.f;
        if (f < NPAIR) {
            int i = 0, r = f;
            while (r >= 25 - i) { r -= 25 - i; ++i; }
            const int j = i + r;
            v = quad_w[((d * 25 + i) * 25 + j) * 16 + n];
            if (i != j) v += quad_w[((d * 25 + j) * 25 + i) * 16 + n];
        } else if (f < NPAIR + 25) {
            const int i = f - NPAIR;
            v = lin_w[i * 64 + d * 16 + n];
        }
        frag[e] = (_Float16)v;
    }
    *(half8*)(fragB + (c * 64 + lane) * 8) = frag;
}

// ---------- compile-time feature generation ----------
template<int F>
__device__ __forceinline__ float featval(const float (&pd)[25]) {
    if constexpr (F < NPAIR) {
        constexpr int i = pair_i(F);
        constexpr int j = pair_j(F);
        return pd[i] * pd[j];
    } else if constexpr (F < NPAIR + 25) {
        return pd[F - NPAIR];
    } else {
        return 0.f;
    }
}

template<int C, size_t... E>
__device__ __forceinline__ half8 make_frag(const float (&pd)[25],
                                           std::index_sequence<E...>) {
    half8 a;
    ((a[E] = (_Float16)featval<C * 8 + (int)E>(pd)), ...);
    return a;
}

template<size_t... Cs>
__device__ __forceinline__ void gemm_chunks(const float (&pd0)[25], const float (&pd1)[25],
                                            const half8* __restrict__ sBv, int lane,
                                            floatx4& acc0, floatx4& acc1,
                                            std::index_sequence<Cs...>) {
    (([&] {
        const half8 af0 = make_frag<(int)Cs>(pd0, std::make_index_sequence<8>{});
        const half8 af1 = make_frag<(int)Cs>(pd1, std::make_index_sequence<8>{});
        const half8 bf = sBv[(int)Cs * 64 + lane];
        acc0 = __builtin_amdgcn_mfma_f32_16x16x32_f16(af0, bf, acc0, 0, 0, 0);
        acc1 = __builtin_amdgcn_mfma_f32_16x16x32_f16(af1, bf, acc1, 0, 0, 0);
    }()), ...);
}

// ---------- main kernel: 32 pixels per wave, 4 waves per block ----------
__global__ __launch_bounds__(256) void convquad_gemm(
    const float* __restrict__ x,       // (8,250,250,4)
    const float* __restrict__ bias,    // (16,)
    const _Float16* __restrict__ fragB,
    float* __restrict__ out)           // (8,250,250,16)
{
    __shared__ _Float16 sB[NCHUNK * 64 * 8];   // 45,056 B

    {   // stage B fragments (block-wide, once)
        const float4* src = (const float4*)fragB;
        float4* dst = (float4*)sB;
        for (int t = threadIdx.x; t < NCHUNK * 64 * 8 / 8; t += 256) dst[t] = src[t];
    }
    __syncthreads();

    const int lane = threadIdx.x & 63;
    const int wave = threadIdx.x >> 6;
    const int m = lane & 15;     // pixel-in-tile (A row); also o for the store
    const int q = lane >> 4;     // channel d for A; row-quad for D
    const int pixbase = blockIdx.x * 128 + wave * 32;

    // ---- per-lane patch of 2 pixels, channel q, statically indexed ----
    float pd0[25], pd1[25];
    #pragma unroll
    for (int t = 0; t < 2; ++t) {
        float (&pd)[25] = t ? pd1 : pd0;
        const int pix = pixbase + t * 16 + m;
        const int pixc = min(pix, NPIX - 1);
        const int w  = pixc % WW;
        const int t1 = pixc / WW;
        const int h  = t1 % HH;
        const int b  = t1 / HH;
        #pragma unroll
        for (int kh = 0; kh < 5; ++kh) {
            const int r = h + kh - 2;
            const float rm = (r >= 0 && r < HH) ? 1.f : 0.f;
            const int rc = min(max(r, 0), HH - 1);
            const int rowb = ((b * HH + rc) * WW) * 4;
            #pragma unroll
            for (int kw = 0; kw < 5; ++kw) {
                const int c = w + kw - 2;
                const float cm = (c >= 0 && c < WW) ? 1.f : 0.f;
                const int cc = min(max(c, 0), WW - 1);
                pd[kh * 5 + kw] = x[rowb + cc * 4 + q] * (rm * cm);
            }
        }
    }

    // ---- GEMM: 44 chunks, features generated in-register (template-unrolled) ----
    floatx4 acc0 = {0.f, 0.f, 0.f, 0.f};
    floatx4 acc1 = {0.f, 0.f, 0.f, 0.f};
    gemm_chunks(pd0, pd1, (const half8*)sB, lane, acc0, acc1,
                std::make_index_sequence<NCHUNK>{});

    // ---- epilogue: D row=q*4+r (pixel), col=m (o) ----
    const float bo = bias[m];
    #pragma unroll
    for (int r = 0; r < 4; ++r) {
        const int p0 = pixbase + q * 4 + r;
        if (p0 < NPIX) out[p0 * NF + m] = acc0[r] + bo;
        const int p1 = pixbase + 16 + q * 4 + r;
        if (p1 < NPIX) out[p1 * NF + m] = acc1[r] + bo;
    }
}

extern "C" void kernel_launch(void* const* d_in, const int* in_sizes, int n_in,
                              void* d_out, int out_size, void* d_ws, size_t ws_size,
                              hipStream_t stream) {
    const float* x      = (const float*)d_in[0];
    const float* lin_w  = (const float*)d_in[1];
    const float* quad_w = (const float*)d_in[2];
    const float* bias   = (const float*)d_in[3];
    float* out = (float*)d_out;
    _Float16* fragB = (_Float16*)d_ws;   // 45,056 B

    prep_frags<<<dim3(NCHUNK), dim3(64), 0, stream>>>(lin_w, quad_w, fragB);

    const int nblocks = (NPIX + 127) / 128;   // 3907 blocks, 32 pix/wave
    convquad_gemm<<<dim3(nblocks), dim3(256), 0, stream>>>(x, bias, fragB, out);
}

// Round 5
// 145.283 us; speedup vs baseline: 7.3924x; 1.1574x over previous
//
#include <hip/hip_runtime.h>
#include <utility>

// ConvQuad2D as ONE pure GEMM over packed-f16 pair-features.
// Round-4 post-mortem: 3,770 VALU/wave (f32 mul -> cvt -> pack per element) +
// LDS-capped occupancy (3 blocks/CU) -> 117us at 41% VALUBusy. Fixes here:
//  1) patch kept as 13 half2 regs; each v_pk_mul_f16 (op_sel broadcast) emits
//     TWO features directly into the A-frag register: 181 ops for 362 pair
//     features, zero cvt/pack; linear features are the patch regs themselves.
//  2) no LDS at all: B-fragments read from global (L2-resident 49KB, one
//     coalesced dwordx4 per chunk per lane); no barrier; VGPR-limited occupancy.
// Feature order (prep kernel owns the matching weights): slot s in [0,196):
//   s<181: pair slot (i, g), g in [i>>1, 12]: features (p_i*p_{2g}, p_i*p_{2g+1});
//          weights: j==i -> Wq[d,i,i]; j>i -> Wq[d,i,j]+Wq[d,j,i]; j<i or j==25 -> 0
//   s<194: linear slot t=s-181: features (p_{2t}, p_{2t+1}); weights Klin[j,d,o]
//   else:  zero pad. k-slot: chunk c = s>>2, lane q = channel d, e = feature in chunk.

typedef _Float16 half2 __attribute__((ext_vector_type(2)));
typedef _Float16 half4 __attribute__((ext_vector_type(4)));
typedef _Float16 half8 __attribute__((ext_vector_type(8)));
typedef float floatx4 __attribute__((ext_vector_type(4)));

#define BB 8
#define HH 250
#define WW 250
#define NPIX (BB * HH * WW)   // 500,000
#define NF 16
#define NSLOT_PAIR 181
#define NSLOT_LIN  13
#define NCHUNK     49         // 49*4 = 196 half2 slots = 392 features/channel

__host__ __device__ constexpr int slot_i(int s) {
    int i = 0, base = 0;
    while (base + (13 - (i >> 1)) <= s) { base += 13 - (i >> 1); ++i; }
    return i;
}
__host__ __device__ constexpr int slot_g(int s) {
    int i = 0, base = 0;
    while (base + (13 - (i >> 1)) <= s) { base += 13 - (i >> 1); ++i; }
    return (i >> 1) + (s - base);
}

// ---------- pre-pass: B fragments in MFMA lane order ----------
__global__ void prep_frags(const float* __restrict__ lin_w,   // (5,5,4,16)
                           const float* __restrict__ quad_w,  // (4,25,25,16)
                           _Float16* __restrict__ fragB) {
    const int c = blockIdx.x;       // 0..48
    const int lane = threadIdx.x;   // 0..63
    const int n = lane & 15;
    const int d = lane >> 4;
    half8 frag;
    #pragma unroll
    for (int e = 0; e < 8; ++e) {
        const int f = c * 8 + e;
        const int s = f >> 1, hf = f & 1;
        float v = 0.f;
        if (s < NSLOT_PAIR) {
            int i = 0, base = 0;
            while (base + (13 - (i >> 1)) <= s) { base += 13 - (i >> 1); ++i; }
            const int g = (i >> 1) + (s - base);
            const int j = 2 * g + hf;
            if (j == i)
                v = quad_w[((d * 25 + i) * 25 + i) * 16 + n];
            else if (j > i && j < 25)
                v = quad_w[((d * 25 + i) * 25 + j) * 16 + n]
                  + quad_w[((d * 25 + j) * 25 + i) * 16 + n];
        } else if (s < NSLOT_PAIR + NSLOT_LIN) {
            const int j = 2 * (s - NSLOT_PAIR) + hf;
            if (j < 25) v = lin_w[(j * 4 + d) * 16 + n];
        }
        frag[e] = (_Float16)v;
    }
    *(half8*)(fragB + (c * 64 + lane) * 8) = frag;
}

// ---------- packed helpers ----------
__device__ __forceinline__ half2 pk(float lo, float hi) {
    return __builtin_bit_cast(half2, __builtin_amdgcn_cvt_pkrtz(lo, hi));
}

template<int S>
__device__ __forceinline__ half2 slotval(const half2 (&pd2)[13]) {
    if constexpr (S < NSLOT_PAIR) {
        constexpr int i = slot_i(S), g = slot_g(S);
        constexpr int ir = i >> 1, ih = i & 1;
        const half2 src = pd2[ir];
        const half2 bi = {src[ih], src[ih]};   // op_sel broadcast
        return bi * pd2[g];                    // v_pk_mul_f16
    } else if constexpr (S < NSLOT_PAIR + NSLOT_LIN) {
        return pd2[S - NSLOT_PAIR];
    } else {
        return half2{(_Float16)0.f, (_Float16)0.f};
    }
}

template<int C>
__device__ __forceinline__ half8 make_frag(const half2 (&pd2)[13]) {
    const half2 a0 = slotval<C * 4 + 0>(pd2);
    const half2 a1 = slotval<C * 4 + 1>(pd2);
    const half2 a2 = slotval<C * 4 + 2>(pd2);
    const half2 a3 = slotval<C * 4 + 3>(pd2);
    const half4 lo = __builtin_shufflevector(a0, a1, 0, 1, 2, 3);
    const half4 hi = __builtin_shufflevector(a2, a3, 0, 1, 2, 3);
    return __builtin_shufflevector(lo, hi, 0, 1, 2, 3, 4, 5, 6, 7);
}

template<size_t... Cs>
__device__ __forceinline__ void gemm_chunks(const half2 (&pdA)[13], const half2 (&pdB)[13],
                                            const _Float16* __restrict__ fb,
                                            floatx4& acc0, floatx4& acc1,
                                            std::index_sequence<Cs...>) {
    (([&] {
        const half8 bf = *(const half8*)(fb + (int)Cs * 64 * 8);
        acc0 = __builtin_amdgcn_mfma_f32_16x16x32_f16(make_frag<(int)Cs>(pdA), bf, acc0, 0, 0, 0);
        acc1 = __builtin_amdgcn_mfma_f32_16x16x32_f16(make_frag<(int)Cs>(pdB), bf, acc1, 0, 0, 0);
    }()), ...);
}

// ---------- patch -> 13 half2 registers ----------
__device__ __forceinline__ void build_patch(const float* __restrict__ x,
                                            int pix, int q, half2 (&pd2)[13]) {
    const int pixc = min(pix, NPIX - 1);
    const int w  = pixc % WW;
    const int t1 = pixc / WW;
    const int h  = t1 % HH;
    const int b  = t1 / HH;
    float pf[26];
    pf[25] = 0.f;
    #pragma unroll
    for (int kh = 0; kh < 5; ++kh) {
        const int r = h + kh - 2;
        const float rm = (r >= 0 && r < HH) ? 1.f : 0.f;
        const int rc = min(max(r, 0), HH - 1);
        const int rowb = ((b * HH + rc) * WW) * 4;
        #pragma unroll
        for (int kw = 0; kw < 5; ++kw) {
            const int c = w + kw - 2;
            const float cm = (c >= 0 && c < WW) ? 1.f : 0.f;
            const int cc = min(max(c, 0), WW - 1);
            pf[kh * 5 + kw] = x[rowb + cc * 4 + q] * (rm * cm);
        }
    }
    #pragma unroll
    for (int t = 0; t < 13; ++t) pd2[t] = pk(pf[2 * t], pf[2 * t + 1]);
}

// ---------- main kernel: 32 pixels per wave, no LDS, no barrier ----------
__global__ __launch_bounds__(256) void convquad_gemm(
    const float* __restrict__ x,       // (8,250,250,4)
    const float* __restrict__ bias,    // (16,)
    const _Float16* __restrict__ fragB,
    float* __restrict__ out)           // (8,250,250,16)
{
    const int lane = threadIdx.x & 63;
    const int m = lane & 15;     // pixel-in-tile (A row); also o for the store
    const int q = lane >> 4;     // channel d for A; row-quad for D
    const int pixbase = blockIdx.x * 128 + (threadIdx.x >> 6) * 32;

    half2 pdA[13], pdB[13];
    build_patch(x, pixbase + m,      q, pdA);
    build_patch(x, pixbase + 16 + m, q, pdB);

    floatx4 acc0 = {0.f, 0.f, 0.f, 0.f};
    floatx4 acc1 = {0.f, 0.f, 0.f, 0.f};
    gemm_chunks(pdA, pdB, fragB + lane * 8, acc0, acc1,
                std::make_index_sequence<NCHUNK>{});

    const float bo = bias[m];
    #pragma unroll
    for (int r = 0; r < 4; ++r) {
        const int p0 = pixbase + q * 4 + r;
        if (p0 < NPIX) out[p0 * NF + m] = acc0[r] + bo;
        const int p1 = pixbase + 16 + q * 4 + r;
        if (p1 < NPIX) out[p1 * NF + m] = acc1[r] + bo;
    }
}

extern "C" void kernel_launch(void* const* d_in, const int* in_sizes, int n_in,
                              void* d_out, int out_size, void* d_ws, size_t ws_size,
                              hipStream_t stream) {
    const float* x      = (const float*)d_in[0];
    const float* lin_w  = (const float*)d_in[1];
    const float* quad_w = (const float*)d_in[2];
    const float* bias   = (const float*)d_in[3];
    float* out = (float*)d_out;
    _Float16* fragB = (_Float16*)d_ws;   // 49*64*8*2 = 50,176 B

    prep_frags<<<dim3(NCHUNK), dim3(64), 0, stream>>>(lin_w, quad_w, fragB);

    const int nblocks = (NPIX + 127) / 128;   // 3907 blocks, 32 pix/wave
    convquad_gemm<<<dim3(nblocks), dim3(256), 0, stream>>>(x, bias, fragB, out);
}

// Round 6
// 137.050 us; speedup vs baseline: 7.8366x; 1.0601x over previous
//
#include <hip/hip_runtime.h>
#include <utility>

// ConvQuad2D as ONE pure GEMM over packed-f16 pair-features.
// r5 post-mortem: 79us main, VGPR=40 -> compiler kept ~1 B-load in flight;
// each chunk was load(200cyc L2) -> 2 MFMA(39cyc): stall-bound at 50%.
// r6: (1) 64 pix/wave (4 acc tiles) -> one bf load feeds 4 MFMAs (2x compute
// per load, half the waves/B-traffic); (2) explicit 8-deep rotating register
// prefetch of bf (compile-time indices) -> 8 loads in flight, latency covered.
// Feature order (prep kernel owns matching weights): slot s in [0,196):
//   s<181: pair slot (i,g), g in [i>>1,12]: (p_i*p_{2g}, p_i*p_{2g+1});
//          weights: j==i -> Wq[d,i,i]; j>i -> Wq[d,i,j]+Wq[d,j,i]; else 0
//   s<194: linear slot t=s-181: (p_{2t},p_{2t+1}); weights Klin[j,d,o]; else pad.
// k-slot: chunk c = s>>2, lane q = channel d, e = feature-in-chunk.

typedef _Float16 half2 __attribute__((ext_vector_type(2)));
typedef _Float16 half4 __attribute__((ext_vector_type(4)));
typedef _Float16 half8 __attribute__((ext_vector_type(8)));
typedef float floatx4 __attribute__((ext_vector_type(4)));

#define BB 8
#define HH 250
#define WW 250
#define NPIX (BB * HH * WW)   // 500,000
#define NF 16
#define NSLOT_PAIR 181
#define NSLOT_LIN  13
#define NCHUNK     49         // 49*4 = 196 half2 slots = 392 features/channel
#define DEPTH      8          // bf prefetch depth (rotating register buffer)

__host__ __device__ constexpr int slot_i(int s) {
    int i = 0, base = 0;
    while (base + (13 - (i >> 1)) <= s) { base += 13 - (i >> 1); ++i; }
    return i;
}
__host__ __device__ constexpr int slot_g(int s) {
    int i = 0, base = 0;
    while (base + (13 - (i >> 1)) <= s) { base += 13 - (i >> 1); ++i; }
    return (i >> 1) + (s - base);
}

// ---------- pre-pass: B fragments in MFMA lane order ----------
__global__ void prep_frags(const float* __restrict__ lin_w,   // (5,5,4,16)
                           const float* __restrict__ quad_w,  // (4,25,25,16)
                           _Float16* __restrict__ fragB) {
    const int c = blockIdx.x;       // 0..48
    const int lane = threadIdx.x;   // 0..63
    const int n = lane & 15;
    const int d = lane >> 4;
    half8 frag;
    #pragma unroll
    for (int e = 0; e < 8; ++e) {
        const int f = c * 8 + e;
        const int s = f >> 1, hf = f & 1;
        float v = 0.f;
        if (s < NSLOT_PAIR) {
            int i = 0, base = 0;
            while (base + (13 - (i >> 1)) <= s) { base += 13 - (i >> 1); ++i; }
            const int g = (i >> 1) + (s - base);
            const int j = 2 * g + hf;
            if (j == i)
                v = quad_w[((d * 25 + i) * 25 + i) * 16 + n];
            else if (j > i && j < 25)
                v = quad_w[((d * 25 + i) * 25 + j) * 16 + n]
                  + quad_w[((d * 25 + j) * 25 + i) * 16 + n];
        } else if (s < NSLOT_PAIR + NSLOT_LIN) {
            const int j = 2 * (s - NSLOT_PAIR) + hf;
            if (j < 25) v = lin_w[(j * 4 + d) * 16 + n];
        }
        frag[e] = (_Float16)v;
    }
    *(half8*)(fragB + (c * 64 + lane) * 8) = frag;
}

// ---------- packed helpers ----------
__device__ __forceinline__ half2 pk(float lo, float hi) {
    return __builtin_bit_cast(half2, __builtin_amdgcn_cvt_pkrtz(lo, hi));
}

template<int S>
__device__ __forceinline__ half2 slotval(const half2 (&pd2)[13]) {
    if constexpr (S < NSLOT_PAIR) {
        constexpr int i = slot_i(S), g = slot_g(S);
        constexpr int ir = i >> 1, ih = i & 1;
        const half2 src = pd2[ir];
        const half2 bi = {src[ih], src[ih]};   // op_sel broadcast
        return bi * pd2[g];                    // v_pk_mul_f16
    } else if constexpr (S < NSLOT_PAIR + NSLOT_LIN) {
        return pd2[S - NSLOT_PAIR];
    } else {
        return half2{(_Float16)0.f, (_Float16)0.f};
    }
}

template<int C>
__device__ __forceinline__ half8 make_frag(const half2 (&pd2)[13]) {
    const half2 a0 = slotval<C * 4 + 0>(pd2);
    const half2 a1 = slotval<C * 4 + 1>(pd2);
    const half2 a2 = slotval<C * 4 + 2>(pd2);
    const half2 a3 = slotval<C * 4 + 3>(pd2);
    const half4 lo = __builtin_shufflevector(a0, a1, 0, 1, 2, 3);
    const half4 hi = __builtin_shufflevector(a2, a3, 0, 1, 2, 3);
    return __builtin_shufflevector(lo, hi, 0, 1, 2, 3, 4, 5, 6, 7);
}

template<int C>
__device__ __forceinline__ half8 load_bf(const _Float16* __restrict__ fb) {
    return *(const half8*)(fb + C * 64 * 8);
}

template<size_t... Ps>
__device__ __forceinline__ void preload_bf(half8 (&buf)[DEPTH],
                                           const _Float16* __restrict__ fb,
                                           std::index_sequence<Ps...>) {
    ((buf[Ps] = load_bf<(int)Ps>(fb)), ...);
}

template<size_t... Cs>
__device__ __forceinline__ void gemm_all(
    const half2 (&p0)[13], const half2 (&p1)[13],
    const half2 (&p2)[13], const half2 (&p3)[13],
    const _Float16* __restrict__ fb,
    floatx4& a0, floatx4& a1, floatx4& a2, floatx4& a3,
    std::index_sequence<Cs...>) {
    half8 buf[DEPTH];
    preload_bf(buf, fb, std::make_index_sequence<DEPTH>{});
    (([&] {
        constexpr int C = (int)Cs;
        const half8 bf = buf[C % DEPTH];
        if constexpr (C + DEPTH < NCHUNK)
            buf[C % DEPTH] = load_bf<C + DEPTH>(fb);   // prefetch before MFMAs
        a0 = __builtin_amdgcn_mfma_f32_16x16x32_f16(make_frag<C>(p0), bf, a0, 0, 0, 0);
        a1 = __builtin_amdgcn_mfma_f32_16x16x32_f16(make_frag<C>(p1), bf, a1, 0, 0, 0);
        a2 = __builtin_amdgcn_mfma_f32_16x16x32_f16(make_frag<C>(p2), bf, a2, 0, 0, 0);
        a3 = __builtin_amdgcn_mfma_f32_16x16x32_f16(make_frag<C>(p3), bf, a3, 0, 0, 0);
    }()), ...);
}

// ---------- patch -> 13 half2 registers ----------
__device__ __forceinline__ void build_patch(const float* __restrict__ x,
                                            int pix, int q, half2 (&pd2)[13]) {
    const int pixc = min(pix, NPIX - 1);
    const int w  = pixc % WW;
    const int t1 = pixc / WW;
    const int h  = t1 % HH;
    const int b  = t1 / HH;
    float pf[26];
    pf[25] = 0.f;
    #pragma unroll
    for (int kh = 0; kh < 5; ++kh) {
        const int r = h + kh - 2;
        const float rm = (r >= 0 && r < HH) ? 1.f : 0.f;
        const int rc = min(max(r, 0), HH - 1);
        const int rowb = ((b * HH + rc) * WW) * 4;
        #pragma unroll
        for (int kw = 0; kw < 5; ++kw) {
            const int c = w + kw - 2;
            const float cm = (c >= 0 && c < WW) ? 1.f : 0.f;
            const int cc = min(max(c, 0), WW - 1);
            pf[kh * 5 + kw] = x[rowb + cc * 4 + q] * (rm * cm);
        }
    }
    #pragma unroll
    for (int t = 0; t < 13; ++t) pd2[t] = pk(pf[2 * t], pf[2 * t + 1]);
}

// ---------- main kernel: 64 pixels per wave, no LDS, no barrier ----------
__global__ __launch_bounds__(256) void convquad_gemm(
    const float* __restrict__ x,       // (8,250,250,4)
    const float* __restrict__ bias,    // (16,)
    const _Float16* __restrict__ fragB,
    float* __restrict__ out)           // (8,250,250,16)
{
    const int lane = threadIdx.x & 63;
    const int m = lane & 15;     // pixel-in-tile (A row); also o for the store
    const int q = lane >> 4;     // channel d for A; row-quad for D
    const int pixbase = blockIdx.x * 256 + (threadIdx.x >> 6) * 64;

    half2 pdA[13], pdB[13], pdC[13], pdD[13];
    build_patch(x, pixbase +  0 + m, q, pdA);
    build_patch(x, pixbase + 16 + m, q, pdB);
    build_patch(x, pixbase + 32 + m, q, pdC);
    build_patch(x, pixbase + 48 + m, q, pdD);

    const float bo = bias[m];
    floatx4 acc0 = {bo, bo, bo, bo};   // bias folded into MFMA C-init
    floatx4 acc1 = acc0, acc2 = acc0, acc3 = acc0;

    gemm_all(pdA, pdB, pdC, pdD, fragB + lane * 8,
             acc0, acc1, acc2, acc3, std::make_index_sequence<NCHUNK>{});

    #pragma unroll
    for (int r = 0; r < 4; ++r) {
        const int p0 = pixbase +  0 + q * 4 + r;
        if (p0 < NPIX) out[p0 * NF + m] = acc0[r];
        const int p1 = pixbase + 16 + q * 4 + r;
        if (p1 < NPIX) out[p1 * NF + m] = acc1[r];
        const int p2 = pixbase + 32 + q * 4 + r;
        if (p2 < NPIX) out[p2 * NF + m] = acc2[r];
        const int p3 = pixbase + 48 + q * 4 + r;
        if (p3 < NPIX) out[p3 * NF + m] = acc3[r];
    }
}

extern "C" void kernel_launch(void* const* d_in, const int* in_sizes, int n_in,
                              void* d_out, int out_size, void* d_ws, size_t ws_size,
                              hipStream_t stream) {
    const float* x      = (const float*)d_in[0];
    const float* lin_w  = (const float*)d_in[1];
    const float* quad_w = (const float*)d_in[2];
    const float* bias   = (const float*)d_in[3];
    float* out = (float*)d_out;
    _Float16* fragB = (_Float16*)d_ws;   // 49*64*8*2 = 50,176 B

    prep_frags<<<dim3(NCHUNK), dim3(64), 0, stream>>>(lin_w, quad_w, fragB);

    const int nblocks = (NPIX + 255) / 256;   // 1954 blocks, 64 pix/wave
    convquad_gemm<<<dim3(nblocks), dim3(256), 0, stream>>>(x, bias, fragB, out);
}